// Round 11
// baseline (16.277 us; speedup 1.0000x reference)
//
#include <hip/hip_runtime.h>

// Problem constants (from reference setup_inputs)
constexpr int B = 512;
constexpr int S = 16384;
constexpr int NTOK = B * S;                      // 8388608
constexpr int TPT = 64;                          // tokens per thread, 16x int4
constexpr int NBLOCKS = NTOK / TPT / 256;        // 512 = 2 blocks/CU
// d_ws: u64 partials[NBLOCKS] (4 KB), packed rc | hc<<21 | mc<<42
// (block sums <= 16384 = 2^14 each; 21-bit fields -> no overflow).

__global__ __launch_bounds__(256) void mpl_main(const int* __restrict__ tokens,
                                                unsigned long long* __restrict__ partials) {
    const int tid = blockIdx.x * 256 + threadIdx.x;
    const int lane = threadIdx.x & 63;
    const int t0 = tid * TPT;

    int toks[TPT + 1];
    const int4* p = reinterpret_cast<const int4*>(tokens + t0);
#pragma unroll
    for (int v = 0; v < TPT / 4; ++v) {
        int4 x = p[v];
        toks[v * 4 + 0] = x.x;
        toks[v * 4 + 1] = x.y;
        toks[v * 4 + 2] = x.z;
        toks[v * 4 + 3] = x.w;
    }

    // Cross-chunk token: lane i+1's first token via shuffle. Rows are 16384
    // tokens = 4 wave-regions (64 lanes x 64 tokens), so only lane 63 can sit
    // at a row boundary; at a row end duplicate our own last token (the
    // duplicated pair contributes 0 to all three counters).
    int nxt = __shfl(toks[0], lane + 1, 64);
    if (lane == 63) {
        const bool rowEnd = ((t0 + TPT) & (S - 1)) == 0;
        nxt = rowEnd ? toks[TPT - 1] : tokens[t0 + TPT];
    }
    toks[TPT] = nxt;

    int rc = 0, hc = 0, mc = 0;
    int qp = 0, pcp = 0, pitp = 0;
#pragma unroll
    for (int j = 0; j <= TPT; ++j) {
        const int t = toks[j];
        const int q = (t + 256) >> 9;            // ts indicator in bit 0 (t<1024)
        const int pit = (t < 128) ? t : 0;       // note-on pitch
        const int pc = pit % 12;
        if (j > 0) {
            rc += (qp ^ q) & 1;                  // time-shift transition
            const int xh = pcp - pc + 11;        // in [0,22]
            hc += (0x00420021u >> xh) & 1;       // pc diff in {-11,-6,6,11}
            const unsigned ym = (unsigned)(pitp - pit + 12);
            mc += (ym > 24u) ? 1 : 0;            // |pitch diff| > 12
        }
        qp = q; pcp = pc; pitp = pit;
    }

    // Wave(64) shuffle reduce: rc,mc packed (wave sums <= 4096 each, fit 16
    // bits), hc alone.
    unsigned int pk = (unsigned)rc | ((unsigned)mc << 16);
    unsigned int hh = (unsigned)hc;
#pragma unroll
    for (int off = 32; off > 0; off >>= 1) {
        pk += __shfl_down(pk, off, 64);
        hh += __shfl_down(hh, off, 64);
    }

    __shared__ unsigned int s[2][4];
    const int wave = threadIdx.x >> 6;
    if ((threadIdx.x & 63) == 0) {
        s[0][wave] = pk;
        s[1][wave] = hh;
    }
    __syncthreads();
    if (threadIdx.x == 0) {
        const unsigned int pks = s[0][0] + s[0][1] + s[0][2] + s[0][3];
        const unsigned int hs  = s[1][0] + s[1][1] + s[1][2] + s[1][3];
        // One 8-byte store per block: rc | hc<<21 | mc<<42.
        partials[blockIdx.x] = (unsigned long long)(pks & 0xFFFFu) |
                               ((unsigned long long)hs << 21) |
                               ((unsigned long long)(pks >> 16) << 42);
    }
}

// Single-wave finalizer: 64 lanes x 8 u64 = all 512 partials in one
// fully-unrolled burst of dwordx4 loads (max MLP, one latency round).
__global__ __launch_bounds__(64) void mpl_reduce(const unsigned long long* __restrict__ partials,
                                                 float* __restrict__ out) {
    const uint4* p4 = reinterpret_cast<const uint4*>(partials);  // 2 u64 per uint4
    unsigned int r = 0, h = 0, m = 0;
#pragma unroll
    for (int k = 0; k < 4; ++k) {                // 4 x uint4 = 8 u64 per lane
        uint4 a = p4[threadIdx.x * 4 + k];
        unsigned long long v0 = (unsigned long long)a.x | ((unsigned long long)a.y << 32);
        unsigned long long v1 = (unsigned long long)a.z | ((unsigned long long)a.w << 32);
        r += (unsigned int)(v0 & 0x1FFFFFull) + (unsigned int)(v1 & 0x1FFFFFull);
        h += (unsigned int)((v0 >> 21) & 0x1FFFFFull) + (unsigned int)((v1 >> 21) & 0x1FFFFFull);
        m += (unsigned int)(v0 >> 42) + (unsigned int)(v1 >> 42);
    }
#pragma unroll
    for (int off = 32; off > 0; off >>= 1) {
        r += __shfl_down(r, off, 64);
        h += __shfl_down(h, off, 64);
        m += __shfl_down(m, off, 64);
    }
    if (threadIdx.x == 0) {
        const double pairs = (double)B * (double)(S - 1);
        const double all = (double)B * (double)S;
        out[0] = (float)((double)r / pairs + (double)h / all + (double)m / pairs);
    }
}

extern "C" void kernel_launch(void* const* d_in, const int* in_sizes, int n_in,
                              void* d_out, int out_size, void* d_ws, size_t ws_size,
                              hipStream_t stream) {
    const int* tokens = (const int*)d_in[0];
    unsigned long long* partials = (unsigned long long*)d_ws;  // 4 KB

    mpl_main<<<NBLOCKS, 256, 0, stream>>>(tokens, partials);
    mpl_reduce<<<1, 64, 0, stream>>>(partials, (float*)d_out);
}

// Round 12
// 15.774 us; speedup vs baseline: 1.0318x; 1.0318x over previous
//
#include <hip/hip_runtime.h>

// Problem constants (from reference setup_inputs)
constexpr int B = 512;
constexpr int S = 16384;
constexpr int NTOK = B * S;                      // 8388608
constexpr int TPT = 32;                          // tokens per thread, 8x int4
constexpr int NBLOCKS = NTOK / TPT / 256;        // 1024 = 4 blocks/CU
// d_ws: u64 partials[NBLOCKS] (8 KB), packed rc | hc<<21 | mc<<42
// (block sums <= 8192 = 2^13 each; 21-bit fields -> no overflow).
//
// Structure notes (measured, rounds R1-R11):
//  - two dispatches beat every single-dispatch completion protocol tried
//    (single-line ticket +11.6us, __threadfence fusion +40us, hierarchical
//    tickets +5us, in-graph memset +12us);
//  - TPT=32/1024 blocks beats TPT=16 (+0.8us) and TPT=64 (+0.7us);
//  - all counts are exact integers -> bit-exact vs reference.

__global__ __launch_bounds__(256) void mpl_main(const int* __restrict__ tokens,
                                                unsigned long long* __restrict__ partials) {
    const int tid = blockIdx.x * 256 + threadIdx.x;
    const int lane = threadIdx.x & 63;
    const int t0 = tid * TPT;

    int toks[TPT + 1];
    const int4* p = reinterpret_cast<const int4*>(tokens + t0);
#pragma unroll
    for (int v = 0; v < TPT / 4; ++v) {
        int4 x = p[v];
        toks[v * 4 + 0] = x.x;
        toks[v * 4 + 1] = x.y;
        toks[v * 4 + 2] = x.z;
        toks[v * 4 + 3] = x.w;
    }

    // Cross-chunk token: lane i+1's first token via shuffle. Rows are 16384
    // tokens = 8 wave-regions, so only lane 63 can sit at a row boundary; at a
    // row end duplicate our own last token (pair contributes 0 everywhere).
    int nxt = __shfl(toks[0], lane + 1, 64);
    if (lane == 63) {
        const bool rowEnd = ((t0 + TPT) & (S - 1)) == 0;
        nxt = rowEnd ? toks[TPT - 1] : tokens[t0 + TPT];
    }
    toks[TPT] = nxt;

    int rc = 0, hc = 0, mc = 0;
    int qp = 0, pcp = 0, pitp = 0;
#pragma unroll
    for (int j = 0; j <= TPT; ++j) {
        const int t = toks[j];
        const int q = (t + 256) >> 9;            // ts indicator in bit 0 (t<1024)
        const int pit = (t < 128) ? t : 0;       // note-on pitch
        const int pc = pit % 12;
        if (j > 0) {
            rc += (qp ^ q) & 1;                  // time-shift transition
            const int xh = pcp - pc + 11;        // in [0,22]
            hc += (0x00420021u >> xh) & 1;       // pc diff in {-11,-6,6,11}
            const unsigned ym = (unsigned)(pitp - pit + 12);
            mc += (ym > 24u) ? 1 : 0;            // |pitch diff| > 12
        }
        qp = q; pcp = pc; pitp = pit;
    }

    // Wave(64) shuffle reduce: rc,mc packed (wave sums <= 2048 each), hc alone.
    unsigned int pk = (unsigned)rc | ((unsigned)mc << 16);
    unsigned int hh = (unsigned)hc;
#pragma unroll
    for (int off = 32; off > 0; off >>= 1) {
        pk += __shfl_down(pk, off, 64);
        hh += __shfl_down(hh, off, 64);
    }

    __shared__ unsigned int s[2][4];
    const int wave = threadIdx.x >> 6;
    if ((threadIdx.x & 63) == 0) {
        s[0][wave] = pk;
        s[1][wave] = hh;
    }
    __syncthreads();
    if (threadIdx.x == 0) {
        const unsigned int pks = s[0][0] + s[0][1] + s[0][2] + s[0][3];
        const unsigned int hs  = s[1][0] + s[1][1] + s[1][2] + s[1][3];
        // One 8-byte store per block: rc | hc<<21 | mc<<42.
        partials[blockIdx.x] = (unsigned long long)(pks & 0xFFFFu) |
                               ((unsigned long long)hs << 21) |
                               ((unsigned long long)(pks >> 16) << 42);
    }
}

// Single-wave finalizer: 64 lanes x 16 u64 = all 1024 partials in one
// fully-unrolled burst of dwordx4 loads (max MLP, one latency round).
__global__ __launch_bounds__(64) void mpl_reduce(const unsigned long long* __restrict__ partials,
                                                 float* __restrict__ out) {
    const uint4* p4 = reinterpret_cast<const uint4*>(partials);  // 2 u64 per uint4
    unsigned int r = 0, h = 0, m = 0;
#pragma unroll
    for (int k = 0; k < 8; ++k) {                // 8 x uint4 = 16 u64 per lane
        uint4 a = p4[threadIdx.x * 8 + k];
        unsigned long long v0 = (unsigned long long)a.x | ((unsigned long long)a.y << 32);
        unsigned long long v1 = (unsigned long long)a.z | ((unsigned long long)a.w << 32);
        r += (unsigned int)(v0 & 0x1FFFFFull) + (unsigned int)(v1 & 0x1FFFFFull);
        h += (unsigned int)((v0 >> 21) & 0x1FFFFFull) + (unsigned int)((v1 >> 21) & 0x1FFFFFull);
        m += (unsigned int)(v0 >> 42) + (unsigned int)(v1 >> 42);
    }
#pragma unroll
    for (int off = 32; off > 0; off >>= 1) {
        r += __shfl_down(r, off, 64);
        h += __shfl_down(h, off, 64);
        m += __shfl_down(m, off, 64);
    }
    if (threadIdx.x == 0) {
        const double pairs = (double)B * (double)(S - 1);
        const double all = (double)B * (double)S;
        out[0] = (float)((double)r / pairs + (double)h / all + (double)m / pairs);
    }
}

extern "C" void kernel_launch(void* const* d_in, const int* in_sizes, int n_in,
                              void* d_out, int out_size, void* d_ws, size_t ws_size,
                              hipStream_t stream) {
    const int* tokens = (const int*)d_in[0];
    unsigned long long* partials = (unsigned long long*)d_ws;  // 8 KB

    mpl_main<<<NBLOCKS, 256, 0, stream>>>(tokens, partials);
    mpl_reduce<<<1, 64, 0, stream>>>(partials, (float*)d_out);
}